// Round 11
// baseline (52.533 us; speedup 1.0000x reference)
//
#include <hip/hip_runtime.h>

#define B_    8
#define CIN   48
#define CQK   6
#define N_    4096
#define CV    64          // padded V channels: 0-47 v, 48 ones, 49-63 zero
#define TI    64          // queries per block
#define TJ    64          // staged j-tile
#define NCH   4           // j-chunks per block
#define JCH   (N_ / NCH)  // 1024
#define TILES (JCH / TJ)  // 16
#define LOG2E 1.4426950408889634f

typedef __attribute__((ext_vector_type(8)))  short short8;
typedef __attribute__((ext_vector_type(4)))  unsigned int uint4v;
typedef __attribute__((ext_vector_type(16))) float f32x16;

__device__ __forceinline__ unsigned short f2bf(float f) {
    unsigned int u = __float_as_uint(f);
    u += 0x7FFFu + ((u >> 16) & 1u);
    return (unsigned short)(u >> 16);
}

// raw v_exp_f32: 2^x in one trans-pipe instruction (K pre-scaled by log2e)
__device__ __forceinline__ float exp2_fast(float x) {
    float r;
    asm("v_exp_f32 %0, %1" : "=v"(r) : "v"(x));
    return r;
}

__device__ __forceinline__ unsigned int cvt_pk_bf16(float a, float b) {
    unsigned int r;
    asm("v_cvt_pk_bf16_f32 %0, %1, %2" : "=v"(r) : "v"(a), "v"(b));
    return r;   // lo = bf16(a), hi = bf16(b)
}

__device__ __forceinline__ void pl32swap(unsigned int& x, unsigned int& y) {
    asm("v_permlane32_swap_b32 %0, %1" : "+v"(x), "+v"(y));
}

// pure-register pack: 4 dwords -> short8
__device__ __forceinline__ short8 mk8(unsigned int w0, unsigned int w1,
                                      unsigned int w2, unsigned int w3) {
    uint4v t = {w0, w1, w2, w3};
    return __builtin_bit_cast(short8, t);
}

// async 16B global -> LDS (wave-uniform LDS base + lane*16, per-lane global src)
__device__ __forceinline__ void cp16(const unsigned short* g, unsigned short* l) {
    __builtin_amdgcn_global_load_lds(
        (const __attribute__((address_space(1))) unsigned int*)g,
        (__attribute__((address_space(3))) unsigned int*)l, 16, 0, 0);
}

// ---------------------------------------------------------------------------
// Prep: 1x1 convs. qB,kB: [B][N][8] bf16 rows (ch 6,7 = 0; k pre-scaled by
// log2e). vB: [B][CV][N] bf16 chan-major (c48 = 1.0 denom, c49-63 = 0) —
// identical OUTPUT semantics to the R7-verified prep; only the work split
// changed.  Grid: B*64 blocks x 512 thr = 64 positions x 8 wave-aligned
// groups: g0 q; g1 k + ch48-63 fill; g2..g7 v[8(g-2) .. 8(g-2)+7].
// ---------------------------------------------------------------------------
__global__ __launch_bounds__(512) void qkv_kernel(
    const float* __restrict__ x,
    const float* __restrict__ Wq, const float* __restrict__ bq,
    const float* __restrict__ Wk, const float* __restrict__ bk,
    const float* __restrict__ Wv, const float* __restrict__ bv,
    unsigned short* __restrict__ qB, unsigned short* __restrict__ kB,
    unsigned short* __restrict__ vB)
{
    __shared__ float sWq[CQK * CIN], sWk[CQK * CIN], sWv[CIN * CIN];
    __shared__ float sbq[CQK], sbk[CQK], sbv[CIN];
    __shared__ float sx[CIN][64];                 // 12 KB x-tile
    const int tid = threadIdx.x;
    for (int idx = tid; idx < CQK * CIN; idx += 512) { sWq[idx] = Wq[idx]; sWk[idx] = Wk[idx]; }
    for (int idx = tid; idx < CIN * CIN; idx += 512) sWv[idx] = Wv[idx];
    if (tid < CQK) { sbq[tid] = bq[tid]; sbk[tid] = bk[tid]; }
    if (tid < CIN) sbv[tid] = bv[tid];

    const int b  = blockIdx.x >> 6;                      // 64 blocks per batch
    const int n0 = (blockIdx.x & 63) << 6;

    // coalesced x-tile load: 48 rows x 16 float4 (768 float4 over 512 thr)
#pragma unroll
    for (int idx = tid; idx < CIN * 16; idx += 512) {
        const int c  = idx >> 4;
        const int j4 = (idx & 15) << 2;
        *(float4*)&sx[c][j4] =
            *(const float4*)&x[((size_t)b * CIN + c) * N_ + n0 + j4];
    }
    __syncthreads();

    const int g  = tid >> 6;       // wave-aligned group 0..7
    const int jl = tid & 63;
    const int n  = n0 + jl;

    if (g == 0) {
        short8 qrow = {0,0,0,0,0,0,0,0};
#pragma unroll
        for (int o = 0; o < CQK; ++o) {
            float sq = sbq[o];
#pragma unroll
            for (int c = 0; c < CIN; ++c) sq += sWq[o * CIN + c] * sx[c][jl];
            qrow[o] = (short)f2bf(sq);
        }
        *(short8*)&qB[((size_t)b * N_ + n) * 8] = qrow;
    } else if (g == 1) {
        short8 krow = {0,0,0,0,0,0,0,0};
#pragma unroll
        for (int o = 0; o < CQK; ++o) {
            float sk = sbk[o];
#pragma unroll
            for (int c = 0; c < CIN; ++c) sk += sWk[o * CIN + c] * sx[c][jl];
            krow[o] = (short)f2bf(sk * LOG2E);    // fold log2e into K
        }
        *(short8*)&kB[((size_t)b * N_ + n) * 8] = krow;
        vB[((size_t)b * CV + 48) * N_ + n] = 0x3F80u;   // bf16(1.0) denom row
#pragma unroll
        for (int o = 49; o < CV; ++o) vB[((size_t)b * CV + o) * N_ + n] = 0;
    } else {
        const int o0 = (g - 2) * 8;
#pragma unroll
        for (int oo = 0; oo < 8; ++oo) {
            const int o = o0 + oo;
            float sv = sbv[o];
#pragma unroll
            for (int c = 0; c < CIN; ++c) sv += sWv[o * CIN + c] * sx[c][jl];
            vB[((size_t)b * CV + o) * N_ + n] = f2bf(sv);
        }
    }
}

// ---------------------------------------------------------------------------
// Fused attention — BYTE-IDENTICAL to the R7-verified kernel (50.5 µs, pass).
// All-MFMA, double-buffered async V staging; __syncthreads() per tile gives
// the vmcnt+lgkm drain AND an IR-level fence.  512 thr = 8 waves =
// [iw 2][chunk 4]; wave owns 32 i over its chunk's 1024 j.
// ---------------------------------------------------------------------------
__global__ __launch_bounds__(512, 4) void attn_kernel(
    const unsigned short* __restrict__ qB, const unsigned short* __restrict__ kB,
    const unsigned short* __restrict__ vB, const float* __restrict__ x,
    const float* __restrict__ gamma, float* __restrict__ out)
{
    __shared__ __align__(16) unsigned short vt[2][NCH][CV][TJ];   // 64 KB exactly
    float (*cbuf)[TI + 1] = (float (*)[TI + 1]) & vt[0][0][0][0]; // alias (post-loop)

    const int tid   = threadIdx.x;
    const int l     = tid & 63;
    const int w     = tid >> 6;
    const int chunk = w & 3;
    const int iw    = w >> 2;
    const int hi    = l >> 5;
    const int li    = l & 31;
    const int b     = blockIdx.x & 7;    // XCD-swizzle: batch <-> XCD
    const int ig    = blockIdx.x >> 3;
    const int i_base = ig * TI;
    const int gx    = (l & 7) ^ ((l >> 3) & 7);   // inverse-swizzle global chunk

    const unsigned short* kg = kB + (size_t)b * N_ * 8;
    const unsigned short* vg = vB + (size_t)b * CV * N_;

    // Q B-frag: lanes hi==0 hold q[ch 0..7][i = i_base + iw*32 + li]; hi lanes 0
    short8 qf = {0,0,0,0,0,0,0,0};
    if (hi == 0)
        qf = *(const short8*)&qB[((size_t)b * N_ + i_base + iw * 32 + li) * 8];

    f32x16 zc, acc0, acc1;
#pragma unroll
    for (int r = 0; r < 16; ++r) { zc[r] = 0.f; acc0[r] = 0.f; acc1[r] = 0.f; }

    // stage V tile (8 KB per chunk, 2 waves x 4 x 1KB DMA) into buffer BF
#define STAGE(BF, J0)                                                          \
    {                                                                          \
        _Pragma("unroll")                                                      \
        for (int s = 0; s < 4; ++s) {                                          \
            const int c = iw * 32 + s * 8 + (l >> 3);                          \
            cp16(&vg[(size_t)c * N_ + (J0) + gx * 8],                          \
                 &vt[BF][chunk][iw * 32 + s * 8][0]);                          \
        }                                                                      \
    }

#define DO_JST(JST, KF, VTC)                                                   \
    {                                                                          \
        f32x16 s = __builtin_amdgcn_mfma_f32_32x32x16_bf16(KF, qf, zc, 0, 0, 0);\
        _Pragma("unroll")                                                      \
        for (int r = 0; r < 16; ++r) s[r] = exp2_fast(s[r]);                   \
        unsigned int c00 = cvt_pk_bf16(s[0],  s[1]);                           \
        unsigned int c10 = cvt_pk_bf16(s[2],  s[3]);                           \
        unsigned int c01 = cvt_pk_bf16(s[4],  s[5]);                           \
        unsigned int c11 = cvt_pk_bf16(s[6],  s[7]);                           \
        unsigned int c02 = cvt_pk_bf16(s[8],  s[9]);                           \
        unsigned int c12 = cvt_pk_bf16(s[10], s[11]);                          \
        unsigned int c03 = cvt_pk_bf16(s[12], s[13]);                          \
        unsigned int c13 = cvt_pk_bf16(s[14], s[15]);                          \
        unsigned int x0 = c00, y0 = c01; pl32swap(x0, y0);                     \
        unsigned int x1 = c10, y1 = c11; pl32swap(x1, y1);                     \
        const short8 pa0 = mk8(x0, x1, y0, y1);                                \
        unsigned int x2 = c02, y2 = c03; pl32swap(x2, y2);                     \
        unsigned int x3 = c12, y3 = c13; pl32swap(x3, y3);                     \
        const short8 pa1 = mk8(x2, x3, y2, y3);                                \
        const char* vrow0 = (const char*)&(VTC)[li][0];                        \
        const char* vrow1 = (const char*)&(VTC)[32 + li][0];                   \
        short8 vf;                                                             \
        vf = *(const short8*)(vrow0 + ((((JST)*4 + 0 + hi) ^ (li & 7)) << 4)); \
        acc0 = __builtin_amdgcn_mfma_f32_32x32x16_bf16(pa0, vf, acc0, 0, 0, 0);\
        vf = *(const short8*)(vrow0 + ((((JST)*4 + 2 + hi) ^ (li & 7)) << 4)); \
        acc0 = __builtin_amdgcn_mfma_f32_32x32x16_bf16(pa1, vf, acc0, 0, 0, 0);\
        vf = *(const short8*)(vrow1 + ((((JST)*4 + 0 + hi) ^ (li & 7)) << 4)); \
        acc1 = __builtin_amdgcn_mfma_f32_32x32x16_bf16(pa0, vf, acc1, 0, 0, 0);\
        vf = *(const short8*)(vrow1 + ((((JST)*4 + 2 + hi) ^ (li & 7)) << 4)); \
        acc1 = __builtin_amdgcn_mfma_f32_32x32x16_bf16(pa1, vf, acc1, 0, 0, 0);\
    }

    // ---- prologue: issue L(0) ----
    const int jbase = chunk * JCH;
    short8 kf0  = {0,0,0,0,0,0,0,0}, kf1  = {0,0,0,0,0,0,0,0};
    short8 kf0n = {0,0,0,0,0,0,0,0}, kf1n = {0,0,0,0,0,0,0,0};
    STAGE(0, jbase)
    if (hi == 0) {
        kf0 = *(const short8*)&kg[(size_t)(jbase + li) * 8];
        kf1 = *(const short8*)&kg[(size_t)(jbase + 32 + li) * 8];
    }

#pragma unroll 1
    for (int t = 0; t < TILES; ++t) {
        const int bf = t & 1;
        // block-wide: everyone's L(t) landed (vmcnt+lgkm drain + real fence)
        __syncthreads();
        // issue L(t+1): safe — buf[bf^1]'s readers (compute t-1) all finished
        // before this barrier; DMA hides under compute(t)
        if (t + 1 < TILES) {
            const int j0n = jbase + (t + 1) * TJ;
            STAGE(bf ^ 1, j0n)
            if (hi == 0) {
                kf0n = *(const short8*)&kg[(size_t)(j0n + li) * 8];
                kf1n = *(const short8*)&kg[(size_t)(j0n + 32 + li) * 8];
            }
        }
        __builtin_amdgcn_s_setprio(1);
        DO_JST(0, kf0, vt[bf][chunk])
        DO_JST(1, kf1, vt[bf][chunk])
        __builtin_amdgcn_s_setprio(0);
        kf0 = kf0n; kf1 = kf1n;
    }
#undef DO_JST
#undef STAGE

    // all compute done before aliasing cbuf onto vt
    __syncthreads();

    // ---- combine 4 chunk partials in LDS (deterministic, serialized) ----
#pragma unroll 1
    for (int r = 0; r < NCH; ++r) {
        if (chunk == r) {
#pragma unroll
            for (int reg = 0; reg < 16; ++reg) {
                const int i_loc = iw * 32 + (reg & 3) + 8 * (reg >> 2) + 4 * hi;
                if (r == 0) {
                    cbuf[li][i_loc]      = acc0[reg];
                    cbuf[32 + li][i_loc] = acc1[reg];
                } else {
                    cbuf[li][i_loc]      += acc0[reg];
                    cbuf[32 + li][i_loc] += acc1[reg];
                }
            }
        }
        __syncthreads();
    }

    // ---- epilogue: out = gamma * acc/l + x ----
    const float gm = gamma[0];
#pragma unroll
    for (int rep = 0; rep < 8; ++rep) {
        const int idx = tid + rep * 512;     // 0..4095
        const int c   = idx >> 6;
        const int i2  = idx & 63;
        if (c < CIN) {
            const size_t off = ((size_t)b * CIN + c) * N_ + i_base + i2;
            out[off] = gm * (cbuf[c][i2] / cbuf[48][i2]) + x[off];
        }
    }
}

extern "C" void kernel_launch(void* const* d_in, const int* in_sizes, int n_in,
                              void* d_out, int out_size, void* d_ws, size_t ws_size,
                              hipStream_t stream)
{
    const float* x     = (const float*)d_in[0];
    const float* Wq    = (const float*)d_in[1];
    const float* bq    = (const float*)d_in[2];
    const float* Wk    = (const float*)d_in[3];
    const float* bk    = (const float*)d_in[4];
    const float* Wv    = (const float*)d_in[5];
    const float* bv    = (const float*)d_in[6];
    const float* gamma = (const float*)d_in[7];
    float* out = (float*)d_out;

    unsigned short* qB = (unsigned short*)d_ws;           // 8*4096*8 = 262144 u16
    unsigned short* kB = qB + (size_t)B_ * N_ * 8;        // 262144 u16
    unsigned short* vB = kB + (size_t)B_ * N_ * 8;        // 8*64*4096 = 2097152 u16
    // ws total: 5,242,880 bytes

    qkv_kernel<<<dim3(B_ * 64), dim3(512), 0, stream>>>(
        x, Wq, bq, Wk, bk, Wv, bv, qB, kB, vB);
    attn_kernel<<<dim3(B_ * 64), dim3(512), 0, stream>>>(
        qB, kB, vB, x, gamma, out);
}

// Round 14
// 50.341 us; speedup vs baseline: 1.0435x; 1.0435x over previous
//
#include <hip/hip_runtime.h>

#define B_    8
#define CIN   48
#define CQK   6
#define N_    4096
#define CV    64          // padded V channels: 0-47 v, 48 ones, 49-63 zero
#define TI    64          // queries per block
#define TJ    64          // staged j-tile
#define NCH   4           // j-chunks per block
#define JCH   (N_ / NCH)  // 1024
#define TILES (JCH / TJ)  // 16
#define LOG2E 1.4426950408889634f

typedef __attribute__((ext_vector_type(8)))  short short8;
typedef __attribute__((ext_vector_type(4)))  unsigned int uint4v;
typedef __attribute__((ext_vector_type(16))) float f32x16;

__device__ __forceinline__ unsigned short f2bf(float f) {
    unsigned int u = __float_as_uint(f);
    u += 0x7FFFu + ((u >> 16) & 1u);
    return (unsigned short)(u >> 16);
}

// raw v_exp_f32: 2^x in one trans-pipe instruction (K pre-scaled by log2e)
__device__ __forceinline__ float exp2_fast(float x) {
    float r;
    asm("v_exp_f32 %0, %1" : "=v"(r) : "v"(x));
    return r;
}

__device__ __forceinline__ unsigned int cvt_pk_bf16(float a, float b) {
    unsigned int r;
    asm("v_cvt_pk_bf16_f32 %0, %1, %2" : "=v"(r) : "v"(a), "v"(b));
    return r;   // lo = bf16(a), hi = bf16(b)
}

__device__ __forceinline__ void pl32swap(unsigned int& x, unsigned int& y) {
    asm("v_permlane32_swap_b32 %0, %1" : "+v"(x), "+v"(y));
}

// pure-register pack: 4 dwords -> short8
__device__ __forceinline__ short8 mk8(unsigned int w0, unsigned int w1,
                                      unsigned int w2, unsigned int w3) {
    uint4v t = {w0, w1, w2, w3};
    return __builtin_bit_cast(short8, t);
}

// async 16B global -> LDS (wave-uniform LDS base + lane*16, per-lane global src)
__device__ __forceinline__ void cp16(const unsigned short* g, unsigned short* l) {
    __builtin_amdgcn_global_load_lds(
        (const __attribute__((address_space(1))) unsigned int*)g,
        (__attribute__((address_space(3))) unsigned int*)l, 16, 0, 0);
}

// ---------------------------------------------------------------------------
// Prep: 1x1 convs. qB,kB: [B][N][8] bf16 rows (ch 6,7 = 0; k pre-scaled by
// log2e). vB: [B][CV][N] bf16 chan-major (c48 = 1.0, c49-63 = 0).
// Grid: B*64 blocks x 256 thr; x-tile staged ONCE in LDS; 4 channel-groups.
// ---------------------------------------------------------------------------
__global__ __launch_bounds__(256) void qkv_kernel(
    const float* __restrict__ x,
    const float* __restrict__ Wq, const float* __restrict__ bq,
    const float* __restrict__ Wk, const float* __restrict__ bk,
    const float* __restrict__ Wv, const float* __restrict__ bv,
    unsigned short* __restrict__ qB, unsigned short* __restrict__ kB,
    unsigned short* __restrict__ vB)
{
    __shared__ float sWq[CQK * CIN], sWk[CQK * CIN], sWv[CIN * CIN];
    __shared__ float sbq[CQK], sbk[CQK], sbv[CIN];
    __shared__ float sx[CIN][64];                 // 12 KB x-tile
    const int tid = threadIdx.x;
    for (int idx = tid; idx < CQK * CIN; idx += 256) { sWq[idx] = Wq[idx]; sWk[idx] = Wk[idx]; }
    for (int idx = tid; idx < CIN * CIN; idx += 256) sWv[idx] = Wv[idx];
    if (tid < CQK) { sbq[tid] = bq[tid]; sbk[tid] = bk[tid]; }
    if (tid < CIN) sbv[tid] = bv[tid];

    const int b  = blockIdx.x >> 6;                      // 64 blocks per batch
    const int n0 = (blockIdx.x & 63) << 6;

    // coalesced x-tile load: 48 rows x 16 float4
#pragma unroll
    for (int idx = tid; idx < CIN * 16; idx += 256) {
        const int c  = idx >> 4;
        const int j4 = (idx & 15) << 2;
        *(float4*)&sx[c][j4] =
            *(const float4*)&x[((size_t)b * CIN + c) * N_ + n0 + j4];
    }
    __syncthreads();

    const int g  = tid >> 6;
    const int jl = tid & 63;
    const int n  = n0 + jl;

    if (g == 0) {
        short8 qrow = {0,0,0,0,0,0,0,0}, krow = {0,0,0,0,0,0,0,0};
#pragma unroll
        for (int o = 0; o < CQK; ++o) {
            float sq = sbq[o], sk = sbk[o];
#pragma unroll
            for (int c = 0; c < CIN; ++c) {
                const float xv = sx[c][jl];
                sq += sWq[o * CIN + c] * xv;
                sk += sWk[o * CIN + c] * xv;
            }
            qrow[o] = (short)f2bf(sq);
            krow[o] = (short)f2bf(sk * LOG2E);    // fold log2e into K
        }
        *(short8*)&qB[((size_t)b * N_ + n) * 8] = qrow;
        *(short8*)&kB[((size_t)b * N_ + n) * 8] = krow;
        vB[((size_t)b * CV + 48) * N_ + n] = 0x3F80u;   // bf16(1.0) denom row
#pragma unroll
        for (int o = 49; o < CV; ++o) vB[((size_t)b * CV + o) * N_ + n] = 0;
    } else {
        const int o0 = (g - 1) * 16;
#pragma unroll
        for (int oo = 0; oo < 16; ++oo) {
            const int o = o0 + oo;
            float sv = sbv[o];
#pragma unroll
            for (int c = 0; c < CIN; ++c) sv += sWv[o * CIN + c] * sx[c][jl];
            vB[((size_t)b * CV + o) * N_ + n] = f2bf(sv);
        }
    }
}

// ---------------------------------------------------------------------------
// Fused attention — the R7-verified kernel (50.5 µs, pass), restored exactly.
// All-MFMA, double-buffered async V staging; __syncthreads() provides the
// vmcnt+lgkm drain AND an IR-level fence.  512 thr = 8 waves =
// [iw 2][chunk 4]; wave owns 32 i over its chunk's 1024 j.
// Per tile t: [__syncthreads -> L(t) landed block-wide] [issue L(t+1)]
// [compute t].  No max-subtraction: chunk partials additive.
// ---------------------------------------------------------------------------
__global__ __launch_bounds__(512, 4) void attn_kernel(
    const unsigned short* __restrict__ qB, const unsigned short* __restrict__ kB,
    const unsigned short* __restrict__ vB, const float* __restrict__ x,
    const float* __restrict__ gamma, float* __restrict__ out)
{
    __shared__ __align__(16) unsigned short vt[2][NCH][CV][TJ];   // 64 KB exactly
    float (*cbuf)[TI + 1] = (float (*)[TI + 1]) & vt[0][0][0][0]; // alias (post-loop)

    const int tid   = threadIdx.x;
    const int l     = tid & 63;
    const int w     = tid >> 6;
    const int chunk = w & 3;
    const int iw    = w >> 2;
    const int hi    = l >> 5;
    const int li    = l & 31;
    const int b     = blockIdx.x & 7;    // XCD-swizzle: batch <-> XCD
    const int ig    = blockIdx.x >> 3;
    const int i_base = ig * TI;
    const int gx    = (l & 7) ^ ((l >> 3) & 7);   // inverse-swizzle global chunk

    const unsigned short* kg = kB + (size_t)b * N_ * 8;
    const unsigned short* vg = vB + (size_t)b * CV * N_;

    // Q B-frag: lanes hi==0 hold q[ch 0..7][i = i_base + iw*32 + li]; hi lanes 0
    short8 qf = {0,0,0,0,0,0,0,0};
    if (hi == 0)
        qf = *(const short8*)&qB[((size_t)b * N_ + i_base + iw * 32 + li) * 8];

    f32x16 zc, acc0, acc1;
#pragma unroll
    for (int r = 0; r < 16; ++r) { zc[r] = 0.f; acc0[r] = 0.f; acc1[r] = 0.f; }

    // stage V tile (8 KB per chunk, 2 waves x 4 x 1KB DMA) into buffer BF
#define STAGE(BF, J0)                                                          \
    {                                                                          \
        _Pragma("unroll")                                                      \
        for (int s = 0; s < 4; ++s) {                                          \
            const int c = iw * 32 + s * 8 + (l >> 3);                          \
            cp16(&vg[(size_t)c * N_ + (J0) + gx * 8],                          \
                 &vt[BF][chunk][iw * 32 + s * 8][0]);                          \
        }                                                                      \
    }

#define DO_JST(JST, KF, VTC)                                                   \
    {                                                                          \
        f32x16 s = __builtin_amdgcn_mfma_f32_32x32x16_bf16(KF, qf, zc, 0, 0, 0);\
        _Pragma("unroll")                                                      \
        for (int r = 0; r < 16; ++r) s[r] = exp2_fast(s[r]);                   \
        unsigned int c00 = cvt_pk_bf16(s[0],  s[1]);                           \
        unsigned int c10 = cvt_pk_bf16(s[2],  s[3]);                           \
        unsigned int c01 = cvt_pk_bf16(s[4],  s[5]);                           \
        unsigned int c11 = cvt_pk_bf16(s[6],  s[7]);                           \
        unsigned int c02 = cvt_pk_bf16(s[8],  s[9]);                           \
        unsigned int c12 = cvt_pk_bf16(s[10], s[11]);                          \
        unsigned int c03 = cvt_pk_bf16(s[12], s[13]);                          \
        unsigned int c13 = cvt_pk_bf16(s[14], s[15]);                          \
        unsigned int x0 = c00, y0 = c01; pl32swap(x0, y0);                     \
        unsigned int x1 = c10, y1 = c11; pl32swap(x1, y1);                     \
        const short8 pa0 = mk8(x0, x1, y0, y1);                                \
        unsigned int x2 = c02, y2 = c03; pl32swap(x2, y2);                     \
        unsigned int x3 = c12, y3 = c13; pl32swap(x3, y3);                     \
        const short8 pa1 = mk8(x2, x3, y2, y3);                                \
        const char* vrow0 = (const char*)&(VTC)[li][0];                        \
        const char* vrow1 = (const char*)&(VTC)[32 + li][0];                   \
        short8 vf;                                                             \
        vf = *(const short8*)(vrow0 + ((((JST)*4 + 0 + hi) ^ (li & 7)) << 4)); \
        acc0 = __builtin_amdgcn_mfma_f32_32x32x16_bf16(pa0, vf, acc0, 0, 0, 0);\
        vf = *(const short8*)(vrow0 + ((((JST)*4 + 2 + hi) ^ (li & 7)) << 4)); \
        acc0 = __builtin_amdgcn_mfma_f32_32x32x16_bf16(pa1, vf, acc0, 0, 0, 0);\
        vf = *(const short8*)(vrow1 + ((((JST)*4 + 0 + hi) ^ (li & 7)) << 4)); \
        acc1 = __builtin_amdgcn_mfma_f32_32x32x16_bf16(pa0, vf, acc1, 0, 0, 0);\
        vf = *(const short8*)(vrow1 + ((((JST)*4 + 2 + hi) ^ (li & 7)) << 4)); \
        acc1 = __builtin_amdgcn_mfma_f32_32x32x16_bf16(pa1, vf, acc1, 0, 0, 0);\
    }

    // ---- prologue: issue L(0) ----
    const int jbase = chunk * JCH;
    short8 kf0  = {0,0,0,0,0,0,0,0}, kf1  = {0,0,0,0,0,0,0,0};
    short8 kf0n = {0,0,0,0,0,0,0,0}, kf1n = {0,0,0,0,0,0,0,0};
    STAGE(0, jbase)
    if (hi == 0) {
        kf0 = *(const short8*)&kg[(size_t)(jbase + li) * 8];
        kf1 = *(const short8*)&kg[(size_t)(jbase + 32 + li) * 8];
    }

#pragma unroll 1
    for (int t = 0; t < TILES; ++t) {
        const int bf = t & 1;
        // block-wide: everyone's L(t) landed (vmcnt+lgkm drain + real fence)
        __syncthreads();
        // issue L(t+1): safe — buf[bf^1]'s readers (compute t-1) all finished
        // before this barrier; DMA hides under compute(t)
        if (t + 1 < TILES) {
            const int j0n = jbase + (t + 1) * TJ;
            STAGE(bf ^ 1, j0n)
            if (hi == 0) {
                kf0n = *(const short8*)&kg[(size_t)(j0n + li) * 8];
                kf1n = *(const short8*)&kg[(size_t)(j0n + 32 + li) * 8];
            }
        }
        __builtin_amdgcn_s_setprio(1);
        DO_JST(0, kf0, vt[bf][chunk])
        DO_JST(1, kf1, vt[bf][chunk])
        __builtin_amdgcn_s_setprio(0);
        kf0 = kf0n; kf1 = kf1n;
    }
#undef DO_JST
#undef STAGE

    // all compute done before aliasing cbuf onto vt
    __syncthreads();

    // ---- combine 4 chunk partials in LDS (deterministic, serialized) ----
#pragma unroll 1
    for (int r = 0; r < NCH; ++r) {
        if (chunk == r) {
#pragma unroll
            for (int reg = 0; reg < 16; ++reg) {
                const int i_loc = iw * 32 + (reg & 3) + 8 * (reg >> 2) + 4 * hi;
                if (r == 0) {
                    cbuf[li][i_loc]      = acc0[reg];
                    cbuf[32 + li][i_loc] = acc1[reg];
                } else {
                    cbuf[li][i_loc]      += acc0[reg];
                    cbuf[32 + li][i_loc] += acc1[reg];
                }
            }
        }
        __syncthreads();
    }

    // ---- epilogue: out = gamma * acc/l + x ----
    const float gm = gamma[0];
#pragma unroll
    for (int rep = 0; rep < 8; ++rep) {
        const int idx = tid + rep * 512;     // 0..4095
        const int c   = idx >> 6;
        const int i2  = idx & 63;
        if (c < CIN) {
            const size_t off = ((size_t)b * CIN + c) * N_ + i_base + i2;
            out[off] = gm * (cbuf[c][i2] / cbuf[48][i2]) + x[off];
        }
    }
}

extern "C" void kernel_launch(void* const* d_in, const int* in_sizes, int n_in,
                              void* d_out, int out_size, void* d_ws, size_t ws_size,
                              hipStream_t stream)
{
    const float* x     = (const float*)d_in[0];
    const float* Wq    = (const float*)d_in[1];
    const float* bq    = (const float*)d_in[2];
    const float* Wk    = (const float*)d_in[3];
    const float* bk    = (const float*)d_in[4];
    const float* Wv    = (const float*)d_in[5];
    const float* bv    = (const float*)d_in[6];
    const float* gamma = (const float*)d_in[7];
    float* out = (float*)d_out;

    unsigned short* qB = (unsigned short*)d_ws;           // 8*4096*8 = 262144 u16
    unsigned short* kB = qB + (size_t)B_ * N_ * 8;        // 262144 u16
    unsigned short* vB = kB + (size_t)B_ * N_ * 8;        // 8*64*4096 = 2097152 u16
    // ws total: 5,242,880 bytes

    qkv_kernel<<<dim3(B_ * 64), dim3(256), 0, stream>>>(
        x, Wq, bq, Wk, bk, Wv, bv, qB, kB, vB);
    attn_kernel<<<dim3(B_ * 64), dim3(512), 0, stream>>>(
        qB, kB, vB, x, gamma, out);
}